// Round 1
// baseline (6933.867 us; speedup 1.0000x reference)
//
#include <hip/hip_runtime.h>
#include <stdint.h>

// GRU: S=512, B=64, D=H=1024, L=2.
// Pipeline-of-kernels design: kernel k runs 4 independent tasks on disjoint
// block groups (64 WGs each):
//   task D: xlin0[t=k]   = x[t]    @ w_ih_0^T + b_ih_0        (t in [0,512))
//   task A: layer-0 GRU step t=k-1 (reads xlin0 ring, h0)
//   task B: xlin1[t=k-2] = out0[t] @ w_ih_1^T + b_ih_1
//   task C: layer-1 GRU step t=k-3 (reads xlin1 ring, h1) -> d_out
// Kernel boundaries provide cross-XCD coherence (no device-scope sync needed).

#define SLEN 512
#define HB   65536      // 64*1024 elems of one (B,H) slab
#define G3   3072

typedef __attribute__((ext_vector_type(8))) short bf16x8;
typedef __attribute__((ext_vector_type(4))) float f32x4;
typedef __attribute__((ext_vector_type(8))) uint16_t u16x8;

__device__ __forceinline__ uint16_t f32_to_bf16(float f) {
  uint32_t u = __float_as_uint(f);
  uint32_t r = u + 0x7FFFu + ((u >> 16) & 1u);
  return (uint16_t)(r >> 16);
}
__device__ __forceinline__ float sigmoid_fast(float x) {
  return 1.0f / (1.0f + __expf(-x));
}
__device__ __forceinline__ float tanh_fast(float x) {
  return 1.0f - 2.0f / (1.0f + __expf(2.0f * x));
}
__device__ __forceinline__ void async_cp16(const void* g, void* l) {
  __builtin_amdgcn_global_load_lds((const __attribute__((address_space(1))) void*)g,
                                   (__attribute__((address_space(3))) void*)l,
                                   16, 0, 0);
}

// ---- prep kernels -----------------------------------------------------------

__global__ __launch_bounds__(256) void convert_x(const float* __restrict__ src,
                                                 uint16_t* __restrict__ dst) {
  size_t i = ((size_t)blockIdx.x * 256 + threadIdx.x) * 8;
  const float4* s = (const float4*)(src + i);
  float4 a = s[0], b = s[1];
  u16x8 v;
  v[0] = f32_to_bf16(a.x); v[1] = f32_to_bf16(a.y);
  v[2] = f32_to_bf16(a.z); v[3] = f32_to_bf16(a.w);
  v[4] = f32_to_bf16(b.x); v[5] = f32_to_bf16(b.y);
  v[6] = f32_to_bf16(b.z); v[7] = f32_to_bf16(b.w);
  *(u16x8*)(dst + i) = v;
}

// Pack weight (3072x1024 row-major f32) into MFMA B-fragment order:
// chunk index = (tile*32 + ks)*64 + lane ; tile covers w rows 16t..16t+15,
// lane holds w[16t + (lane&15)][32ks + (lane>>4)*8 .. +7] as 8 bf16 (16B).
__global__ __launch_bounds__(256) void pack_w(const float* __restrict__ src,
                                              uint16_t* __restrict__ dst) {
  int tid = blockIdx.x * 256 + threadIdx.x;    // < 192*32*64 = 393216
  int tile = tid >> 11;
  int rem  = tid & 2047;
  int ks   = rem >> 6;
  int lane = rem & 63;
  int row  = tile * 16 + (lane & 15);
  int k0   = ks * 32 + (lane >> 4) * 8;
  const float* s = src + (size_t)row * 1024 + k0;
  u16x8 v;
#pragma unroll
  for (int j = 0; j < 8; ++j) v[j] = f32_to_bf16(s[j]);
  *(u16x8*)(dst + (size_t)tid * 8) = v;
}

__global__ __launch_bounds__(256) void init_state(const float* __restrict__ hx,
                                                  float* __restrict__ h0f, float* __restrict__ h1f,
                                                  uint16_t* __restrict__ h0b, uint16_t* __restrict__ h1b) {
  int i = blockIdx.x * 256 + threadIdx.x;      // 65536 threads
  float a = hx[i], b = hx[HB + i];
  h0f[i] = a; h1f[i] = b;
  h0b[i] = f32_to_bf16(a);   // buffer 0 (read at t=0)
  h1b[i] = f32_to_bf16(b);
}

__global__ __launch_bounds__(256) void finalize(const float* __restrict__ h0f,
                                                const float* __restrict__ h1f,
                                                float* __restrict__ out) {
  int i = blockIdx.x * 256 + threadIdx.x;      // 131072 threads
  out[(size_t)SLEN * HB + i] = (i < HB) ? h0f[i] : h1f[i - HB];
}

// ---- pipelined step kernel --------------------------------------------------

__global__ __launch_bounds__(256, 1) void gru_step(
    int k,
    const uint16_t* __restrict__ x_bf,
    const uint16_t* __restrict__ wih0, const uint16_t* __restrict__ whh0,
    const uint16_t* __restrict__ wih1, const uint16_t* __restrict__ whh1,
    const float* __restrict__ bih0, const float* __restrict__ bhh0,
    const float* __restrict__ bih1, const float* __restrict__ bhh1,
    float* __restrict__ xl0, float* __restrict__ xl1,
    uint16_t* __restrict__ o0r,
    uint16_t* __restrict__ h0b, uint16_t* __restrict__ h1b,
    float* __restrict__ h0f, float* __restrict__ h1f,
    float* __restrict__ out) {
  __shared__ uint16_t lds[32768];              // 64 KB: 4 waves x 16 rows x 512 k (bf16)

  const int task  = blockIdx.x >> 6;
  const int slice = blockIdx.x & 63;
  int t;
  const uint16_t* Asrc;
  const uint16_t* Bw;
  if (task == 0)      { t = k;     if (t >= SLEN) return;          Asrc = x_bf + (size_t)t * HB;      Bw = wih0; }
  else if (task == 1) { t = k - 1; if (t < 0 || t >= SLEN) return; Asrc = h0b + (size_t)(t & 1) * HB; Bw = whh0; }
  else if (task == 2) { t = k - 2; if (t < 0 || t >= SLEN) return; Asrc = o0r + (size_t)(t & 3) * HB; Bw = wih1; }
  else                { t = k - 3; if (t < 0 || t >= SLEN) return; Asrc = h1b + (size_t)(t & 1) * HB; Bw = whh1; }

  const int lane = threadIdx.x & 63;
  const int wv   = threadIdx.x >> 6;
  const int r15  = lane & 15;
  const int q    = lane >> 4;

  f32x4 acc0 = {0.f,0.f,0.f,0.f}, acc1 = acc0, acc2 = acc0;

  // packed B pointers: tile = g*64 + slice ; one (tile,ks) chunk = 512 shorts
  const uint16_t* bp0 = Bw + (size_t)(0 * 64 + slice) * 16384 + lane * 8;
  const uint16_t* bp1 = Bw + (size_t)(1 * 64 + slice) * 16384 + lane * 8;
  const uint16_t* bp2 = Bw + (size_t)(2 * 64 + slice) * 16384 + lane * 8;

  uint16_t* lbase = &lds[wv * 8192];           // this wave's 16 KB region

  for (int kc = 0; kc < 2; ++kc) {
    // stage A rows 16*wv..16*wv+15, k in [kc*512, kc*512+512), XOR-swizzled source
    const uint16_t* asrc_w = Asrc + (size_t)(16 * wv) * 1024 + kc * 512;
#pragma unroll
    for (int i = 0; i < 16; ++i) {
      const uint16_t* gp = asrc_w + (size_t)i * 1024 + ((lane ^ (i & 7)) * 8);
      async_cp16(gp, lbase + i * 512);
    }
    __syncthreads();                           // drains vmcnt (staging) + lgkmcnt
#pragma unroll 4
    for (int ks = 0; ks < 16; ++ks) {
      int chunk = (ks * 4 + q) ^ (r15 & 7);
      bf16x8 a  = *(const bf16x8*)(lbase + r15 * 512 + chunk * 8);
      bf16x8 b0 = *(const bf16x8*)bp0;
      bf16x8 b1 = *(const bf16x8*)bp1;
      bf16x8 b2 = *(const bf16x8*)bp2;
      bp0 += 512; bp1 += 512; bp2 += 512;
      acc0 = __builtin_amdgcn_mfma_f32_16x16x32_bf16(a, b0, acc0, 0, 0, 0);
      acc1 = __builtin_amdgcn_mfma_f32_16x16x32_bf16(a, b1, acc1, 0, 0, 0);
      acc2 = __builtin_amdgcn_mfma_f32_16x16x32_bf16(a, b2, acc2, 0, 0, 0);
    }
    __syncthreads();
  }

  const int c = slice * 16 + r15;              // h-column 0..1023
  const int m = 16 * wv + 4 * q;               // batch row base (+reg)

  if (task == 0 || task == 2) {
    const float* bih = (task == 0) ? bih0 : bih1;
    float* dst = ((task == 0) ? xl0 : xl1) + (size_t)(t & 3) * 64 * G3;
    float br = bih[c], bz = bih[1024 + c], bn = bih[2048 + c];
#pragma unroll
    for (int rg = 0; rg < 4; ++rg) {
      int mm = m + rg;
      dst[(size_t)mm * G3 + c]        = acc0[rg] + br;
      dst[(size_t)mm * G3 + 1024 + c] = acc1[rg] + bz;
      dst[(size_t)mm * G3 + 2048 + c] = acc2[rg] + bn;
    }
  } else {
    const float* xl  = ((task == 1) ? xl0 : xl1) + (size_t)(t & 3) * 64 * G3;
    const float* bhh = (task == 1) ? bhh0 : bhh1;
    float* hf        = (task == 1) ? h0f : h1f;
    uint16_t* hbw    = ((task == 1) ? h0b : h1b) + (size_t)((t + 1) & 1) * HB;
    float br = bhh[c], bz = bhh[1024 + c], bn = bhh[2048 + c];
#pragma unroll
    for (int rg = 0; rg < 4; ++rg) {
      int mm = m + rg;
      float xr = xl[(size_t)mm * G3 + c];
      float xz = xl[(size_t)mm * G3 + 1024 + c];
      float xn = xl[(size_t)mm * G3 + 2048 + c];
      float hp = hf[mm * 1024 + c];
      float r  = sigmoid_fast(xr + acc0[rg] + br);
      float z  = sigmoid_fast(xz + acc1[rg] + bz);
      float n  = tanh_fast(xn + r * (acc2[rg] + bn));
      float h  = (1.0f - z) * n + z * hp;
      hf[mm * 1024 + c] = h;
      uint16_t hb16 = f32_to_bf16(h);
      hbw[mm * 1024 + c] = hb16;
      if (task == 1) o0r[(size_t)(t & 3) * HB + mm * 1024 + c] = hb16;
      else           out[(size_t)t * HB + mm * 1024 + c] = h;
    }
  }
}

// ---- host -------------------------------------------------------------------

extern "C" void kernel_launch(void* const* d_in, const int* in_sizes, int n_in,
                              void* d_out, int out_size, void* d_ws, size_t ws_size,
                              hipStream_t stream) {
  (void)in_sizes; (void)n_in; (void)out_size; (void)ws_size;
  const float* x     = (const float*)d_in[0];
  const float* hx    = (const float*)d_in[1];
  const float* wih0f = (const float*)d_in[2];
  const float* whh0f = (const float*)d_in[3];
  const float* bih0  = (const float*)d_in[4];
  const float* bhh0  = (const float*)d_in[5];
  const float* wih1f = (const float*)d_in[6];
  const float* whh1f = (const float*)d_in[7];
  const float* bih1  = (const float*)d_in[8];
  const float* bhh1  = (const float*)d_in[9];
  float* out = (float*)d_out;

  char* ws = (char*)d_ws;
  uint16_t* x_bf = (uint16_t*)ws; ws += (size_t)SLEN * HB * 2;   // 64 MB
  uint16_t* wih0 = (uint16_t*)ws; ws += (size_t)G3 * 1024 * 2;   // 6 MB each
  uint16_t* whh0 = (uint16_t*)ws; ws += (size_t)G3 * 1024 * 2;
  uint16_t* wih1 = (uint16_t*)ws; ws += (size_t)G3 * 1024 * 2;
  uint16_t* whh1 = (uint16_t*)ws; ws += (size_t)G3 * 1024 * 2;
  float* xl0 = (float*)ws;  ws += (size_t)4 * 64 * G3 * 4;       // 3 MB ring
  float* xl1 = (float*)ws;  ws += (size_t)4 * 64 * G3 * 4;
  uint16_t* o0r = (uint16_t*)ws; ws += (size_t)4 * HB * 2;       // 512 KB ring
  uint16_t* h0b = (uint16_t*)ws; ws += (size_t)2 * HB * 2;
  uint16_t* h1b = (uint16_t*)ws; ws += (size_t)2 * HB * 2;
  float* h0f = (float*)ws; ws += (size_t)HB * 4;
  float* h1f = (float*)ws; ws += (size_t)HB * 4;

  convert_x<<<16384, 256, 0, stream>>>(x, x_bf);
  pack_w<<<1536, 256, 0, stream>>>(wih0f, wih0);
  pack_w<<<1536, 256, 0, stream>>>(whh0f, whh0);
  pack_w<<<1536, 256, 0, stream>>>(wih1f, wih1);
  pack_w<<<1536, 256, 0, stream>>>(whh1f, whh1);
  init_state<<<256, 256, 0, stream>>>(hx, h0f, h1f, h0b, h1b);

  for (int k = 0; k <= SLEN + 2; ++k) {
    gru_step<<<256, 256, 0, stream>>>(k, x_bf, wih0, whh0, wih1, whh1,
                                      bih0, bhh0, bih1, bhh1,
                                      xl0, xl1, o0r, h0b, h1b, h0f, h1f, out);
  }
  finalize<<<512, 256, 0, stream>>>(h0f, h1f, out);
}